// Round 1
// baseline (3292.804 us; speedup 1.0000x reference)
//
#include <hip/hip_runtime.h>

#define UNITS   128
#define TSTEPS  256
#define UNFOLDS 6
#define NB      2      // batch elements per block
#define NC      8      // i-chunks (threads per j)
#define CPT     16     // i's per thread
#define LOG2E   1.4426950408889634f

__device__ __forceinline__ float rcp_f(float x){
#if __has_builtin(__builtin_amdgcn_rcpf)
  return __builtin_amdgcn_rcpf(x);
#else
  return 1.0f / x;
#endif
}
__device__ __forceinline__ float exp2_f(float x){
#if __has_builtin(__builtin_amdgcn_exp2f)
  return __builtin_amdgcn_exp2f(x);
#else
  return __expf(x * 0.6931471805599453f);
#endif
}

// one (i,j,b) synapse: y = mu*s*log2e - v*s*log2e ; sig = 1/(1+2^y)
#define ELEM(vv, kk, NUM, DEN)                                 \
  {                                                            \
    float y_  = fmaf((vv), ns2[kk], m2[kk]);                   \
    float e_  = exp2_f(y_);                                    \
    float sg_ = rcp_f(1.0f + e_);                              \
    NUM = fmaf(wn[kk], sg_, NUM);                              \
    DEN = fmaf(wd[kk], sg_, DEN);                              \
  }

__global__ __launch_bounds__(1024, 4) void ltc_fused(
    const float* __restrict__ x,
    const float* __restrict__ gleak,
    const float* __restrict__ vleak,
    const float* __restrict__ cm,
    const float* __restrict__ sigma,
    const float* __restrict__ mu,
    const float* __restrict__ w_syn,
    const float* __restrict__ erev,
    const float* __restrict__ s_sigma,
    const float* __restrict__ s_mu,
    const float* __restrict__ s_w,
    const float* __restrict__ s_erev,
    const float* __restrict__ input_w,
    const float* __restrict__ input_b,
    const float* __restrict__ output_w,
    const float* __restrict__ output_b,
    const float* __restrict__ fc_w,
    const float* __restrict__ fc_b,
    float* __restrict__ out)
{
  __shared__ __align__(16) float vbuf[2][NB][UNITS];  // ping-pong state
  __shared__ float xs[NB][TSTEPS];
  __shared__ float red[NB][UNITS];

  const int tid = threadIdx.x;
  const int j   = tid >> 3;    // post-synaptic unit (0..127)
  const int c   = tid & 7;     // i-chunk (0..7)
  const int b0  = blockIdx.x * NB;

  // stage the whole input sequence for both batch elements (coalesced)
  if (tid < NB * TSTEPS) {
    int bb = tid >> 8;
    int tt = tid & (TSTEPS - 1);
    xs[bb][tt] = x[(b0 + bb) * TSTEPS + tt];
  }
  if (tid < NB * UNITS) {
    vbuf[0][tid >> 7][tid & (UNITS - 1)] = 0.0f;
  }

  // per-thread register-resident synapse params for (i in chunk, j)
  float ns2[CPT], m2[CPT], wn[CPT], wd[CPT];
#pragma unroll
  for (int k = 0; k < CPT; ++k) {
    int idx = (c * CPT + k) * UNITS + j;     // row = pre(i), col = post(j)
    float sg = sigma[idx] * LOG2E;
    ns2[k] = -sg;
    m2[k]  = mu[idx] * sg;
    float w = w_syn[idx];
    wn[k] = w * erev[idx];
    wd[k] = w;
  }

  // per-thread (per-j) scalars
  const float ss2  = s_sigma[j] * LOG2E;
  const float sm2  = s_mu[j] * ss2;
  const float sw_  = s_w[j];
  const float se_  = s_erev[j];
  const float gl   = gleak[j];
  const float glvl = gl * vleak[j];
  const float cmt  = cm[j] * (float)UNFOLDS;
  const float iw   = input_w[0];
  const float ib   = input_b[0];

  __syncthreads();

  int cur = 0;
  for (int t = 0; t < TSTEPS; ++t) {
    // sensory conductances (fixed within unfolds), computed redundantly per thread
    float snum0, sden0, snum1, sden1;
    {
      float u = fmaf(xs[0][t], iw, ib);
      float e = exp2_f(sm2 - u * ss2);
      float a = sw_ * rcp_f(1.0f + e);
      snum0 = a * se_; sden0 = a;
      u = fmaf(xs[1][t], iw, ib);
      e = exp2_f(sm2 - u * ss2);
      a = sw_ * rcp_f(1.0f + e);
      snum1 = a * se_; sden1 = a;
    }
    for (int r = 0; r < UNFOLDS; ++r) {
      const float* __restrict__ v0 = vbuf[cur][0];
      const float* __restrict__ v1 = vbuf[cur][1];
      float num0 = 0.f, den0 = 0.f, num1 = 0.f, den1 = 0.f;
#pragma unroll
      for (int k = 0; k < CPT; k += 4) {
        float4 a4 = *(const float4*)&v0[c * CPT + k];  // LDS broadcast
        float4 b4 = *(const float4*)&v1[c * CPT + k];
        ELEM(a4.x, k + 0, num0, den0);
        ELEM(a4.y, k + 1, num0, den0);
        ELEM(a4.z, k + 2, num0, den0);
        ELEM(a4.w, k + 3, num0, den0);
        ELEM(b4.x, k + 0, num1, den1);
        ELEM(b4.y, k + 1, num1, den1);
        ELEM(b4.z, k + 2, num1, den1);
        ELEM(b4.w, k + 3, num1, den1);
      }
      // butterfly reduce over the 8 lanes (same j, consecutive lanes)
#pragma unroll
      for (int m = 1; m < NC; m <<= 1) {
        num0 += __shfl_xor(num0, m, 64);
        den0 += __shfl_xor(den0, m, 64);
        num1 += __shfl_xor(num1, m, 64);
        den1 += __shfl_xor(den1, m, 64);
      }
      const int nxt = cur ^ 1;
      float vj0 = vbuf[cur][0][j];
      float vj1 = vbuf[cur][1][j];
      float nv0 = (fmaf(cmt, vj0, glvl) + (num0 + snum0)) *
                  rcp_f(cmt + gl + (den0 + sden0) + 1e-8f);
      float nv1 = (fmaf(cmt, vj1, glvl) + (num1 + snum1)) *
                  rcp_f(cmt + gl + (den1 + sden1) + 1e-8f);
      if (c == 0) {
        vbuf[nxt][0][j] = nv0;
        vbuf[nxt][1][j] = nv1;
      }
      __syncthreads();
      cur = nxt;
    }
  }

  // readout: out[b] = sum_j (v[j]*ow[j]+ob[j]) * fc_w[j] + fc_b
  if (c == 0) {
    float ow = output_w[j], ob = output_b[j], fw = fc_w[j];
    red[0][j] = fmaf(vbuf[cur][0][j], ow, ob) * fw;
    red[1][j] = fmaf(vbuf[cur][1][j], ow, ob) * fw;
  }
  __syncthreads();
  if (tid < NB) {
    float s = fc_b[0];
    const float* rr = red[tid];
    for (int q = 0; q < UNITS; ++q) s += rr[q];
    out[b0 + tid] = s;
  }
}

extern "C" void kernel_launch(void* const* d_in, const int* in_sizes, int n_in,
                              void* d_out, int out_size, void* d_ws, size_t ws_size,
                              hipStream_t stream) {
  const float* x       = (const float*)d_in[0];
  const float* gleak   = (const float*)d_in[1];
  const float* vleak   = (const float*)d_in[2];
  const float* cm      = (const float*)d_in[3];
  const float* sigma   = (const float*)d_in[4];
  const float* mu      = (const float*)d_in[5];
  const float* w_syn   = (const float*)d_in[6];
  const float* erev    = (const float*)d_in[7];
  const float* s_sigma = (const float*)d_in[8];
  const float* s_mu    = (const float*)d_in[9];
  const float* s_w     = (const float*)d_in[10];
  const float* s_erev  = (const float*)d_in[11];
  const float* input_w = (const float*)d_in[12];
  const float* input_b = (const float*)d_in[13];
  const float* out_w   = (const float*)d_in[14];
  const float* out_b   = (const float*)d_in[15];
  const float* fc_w    = (const float*)d_in[16];
  const float* fc_b    = (const float*)d_in[17];

  dim3 grid(512 / NB);
  dim3 block(1024);
  hipLaunchKernelGGL(ltc_fused, grid, block, 0, stream,
                     x, gleak, vleak, cm, sigma, mu, w_syn, erev,
                     s_sigma, s_mu, s_w, s_erev, input_w, input_b,
                     out_w, out_b, fc_w, fc_b, (float*)d_out);
}

// Round 2
// 3127.924 us; speedup vs baseline: 1.0527x; 1.0527x over previous
//
#include <hip/hip_runtime.h>

#define UNITS   128
#define TSTEPS  256
#define UNFOLDS 6
#define NB      2      // batch elements per block
#define NC      8      // i-chunks (threads per j)
#define CPT     16     // i's per thread
#define LOG2E   1.4426950408889634f
#define VPAD    160    // padded v row: 128 + 4 pad per 16
#define IDX(i)  ((i) + (((i) >> 4) << 2))

__device__ __forceinline__ float rcp_f(float x){
#if __has_builtin(__builtin_amdgcn_rcpf)
  return __builtin_amdgcn_rcpf(x);
#else
  return 1.0f / x;
#endif
}
__device__ __forceinline__ float exp2_f(float x){
#if __has_builtin(__builtin_amdgcn_exp2f)
  return __builtin_amdgcn_exp2f(x);
#else
  return __expf(x * 0.6931471805599453f);
#endif
}

// butterfly sum over the 8 consecutive lanes sharing one j:
// xor1, xor2 via quad_perm; xor7 (= other quad of the 8-group) via row_half_mirror
#define DPP_RED(x)                                                                                   \
  asm("v_add_f32_dpp %0, %1, %1 quad_perm:[1,0,3,2] row_mask:0xf bank_mask:0xf" : "=v"(x) : "v"(x)); \
  asm("v_add_f32_dpp %0, %1, %1 quad_perm:[2,3,0,1] row_mask:0xf bank_mask:0xf" : "=v"(x) : "v"(x)); \
  asm("v_add_f32_dpp %0, %1, %1 row_half_mirror row_mask:0xf bank_mask:0xf"     : "=v"(x) : "v"(x));

// one (i,j,b) synapse: y = (mu - v)*sigma*log2e ; sig = 1/(1+2^y)
#define ELEM(vv, kk, NUM, DEN)                                 \
  {                                                            \
    float y_  = fmaf((vv), ns2[kk], m2[kk]);                   \
    float e_  = exp2_f(y_);                                    \
    float sg_ = rcp_f(1.0f + e_);                              \
    NUM = fmaf(wn[kk], sg_, NUM);                              \
    DEN = fmaf(wd[kk], sg_, DEN);                              \
  }

__global__ __launch_bounds__(1024, 2) void ltc_fused(
    const float* __restrict__ x,
    const float* __restrict__ gleak,
    const float* __restrict__ vleak,
    const float* __restrict__ cm,
    const float* __restrict__ sigma,
    const float* __restrict__ mu,
    const float* __restrict__ w_syn,
    const float* __restrict__ erev,
    const float* __restrict__ s_sigma,
    const float* __restrict__ s_mu,
    const float* __restrict__ s_w,
    const float* __restrict__ s_erev,
    const float* __restrict__ input_w,
    const float* __restrict__ input_b,
    const float* __restrict__ output_w,
    const float* __restrict__ output_b,
    const float* __restrict__ fc_w,
    const float* __restrict__ fc_b,
    float* __restrict__ out)
{
  __shared__ __align__(16) float vbuf[2][NB][VPAD];  // ping-pong state, bank-padded
  __shared__ float xs[NB][TSTEPS];
  __shared__ float red[NB][UNITS];

  const int tid = threadIdx.x;
  const int j   = tid >> 3;    // post-synaptic unit (0..127)
  const int c   = tid & 7;     // i-chunk (0..7)
  const int b0  = blockIdx.x * NB;

  // stage the whole input sequence for both batch elements (coalesced)
  if (tid < NB * TSTEPS) {
    int bb = tid >> 8;
    int tt = tid & (TSTEPS - 1);
    xs[bb][tt] = x[(b0 + bb) * TSTEPS + tt];
  }
  if (tid < NB * UNITS) {
    vbuf[0][tid >> 7][IDX(tid & (UNITS - 1))] = 0.0f;
  }

  // per-thread register-resident synapse params for (i in chunk, j)
  float ns2[CPT], m2[CPT], wn[CPT], wd[CPT];
#pragma unroll
  for (int k = 0; k < CPT; ++k) {
    int idx = (c * CPT + k) * UNITS + j;     // row = pre(i), col = post(j)
    float sg = sigma[idx] * LOG2E;
    ns2[k] = -sg;
    m2[k]  = mu[idx] * sg;
    float w = w_syn[idx];
    wn[k] = w * erev[idx];
    wd[k] = w;
  }

  // per-thread (per-j) scalars
  const float ss2n  = -s_sigma[j] * LOG2E;
  const float sm2   = s_mu[j] * (-ss2n);
  const float sw8   = s_w[j] * 0.125f;      // pre-divided by 8 for the lane-sum fold
  const float se_   = s_erev[j];
  const float gl    = gleak[j];
  const float glvl  = gl * vleak[j];
  const float cmt   = cm[j] * (float)UNFOLDS;
  const float dbase = cmt + gl + 1e-8f;
  const float iw    = input_w[0];
  const float ib    = input_b[0];

  __syncthreads();

  int cur = 0;
  const int cb = c * 20;  // padded chunk base (c*16 + c*4)
  for (int t = 0; t < TSTEPS; ++t) {
    // sensory conductances (fixed within unfolds), redundant per thread,
    // pre-scaled by 1/8 so the 8-lane butterfly sum restores them once
    float snum0, sden0, snum1, sden1;
    {
      float u = fmaf(xs[0][t], iw, ib);
      float e = exp2_f(fmaf(u, ss2n, sm2));
      float a = sw8 * rcp_f(1.0f + e);
      snum0 = a * se_; sden0 = a;
      u = fmaf(xs[1][t], iw, ib);
      e = exp2_f(fmaf(u, ss2n, sm2));
      a = sw8 * rcp_f(1.0f + e);
      snum1 = a * se_; sden1 = a;
    }
    for (int r = 0; r < UNFOLDS; ++r) {
      const float* __restrict__ v0 = vbuf[cur][0];
      const float* __restrict__ v1 = vbuf[cur][1];
      float vj0 = v0[IDX(j)];
      float vj1 = v1[IDX(j)];
      float num0 = snum0, den0 = sden0, num1 = snum1, den1 = sden1;
#pragma unroll
      for (int k = 0; k < CPT; k += 4) {
        float4 a4 = *(const float4*)&v0[cb + k];  // conflict-free broadcast
        float4 b4 = *(const float4*)&v1[cb + k];
        ELEM(a4.x, k + 0, num0, den0);
        ELEM(a4.y, k + 1, num0, den0);
        ELEM(a4.z, k + 2, num0, den0);
        ELEM(a4.w, k + 3, num0, den0);
        ELEM(b4.x, k + 0, num1, den1);
        ELEM(b4.y, k + 1, num1, den1);
        ELEM(b4.z, k + 2, num1, den1);
        ELEM(b4.w, k + 3, num1, den1);
      }
      // butterfly reduce over the 8 lanes sharing j — pure VALU, no LDS
      DPP_RED(num0); DPP_RED(den0); DPP_RED(num1); DPP_RED(den1);

      const int nxt = cur ^ 1;
      float nv0 = (fmaf(cmt, vj0, glvl) + num0) * rcp_f(dbase + den0);
      float nv1 = (fmaf(cmt, vj1, glvl) + num1) * rcp_f(dbase + den1);
      if (c == 0) {
        vbuf[nxt][0][IDX(j)] = nv0;
        vbuf[nxt][1][IDX(j)] = nv1;
      }
      __syncthreads();
      cur = nxt;
    }
  }

  // readout: out[b] = sum_j (v[j]*ow[j]+ob[j]) * fc_w[j] + fc_b
  if (c == 0) {
    float ow = output_w[j], ob = output_b[j], fw = fc_w[j];
    red[0][j] = fmaf(vbuf[cur][0][IDX(j)], ow, ob) * fw;
    red[1][j] = fmaf(vbuf[cur][1][IDX(j)], ow, ob) * fw;
  }
  __syncthreads();
  if (tid < NB) {
    float s = fc_b[0];
    const float* rr = red[tid];
    for (int q = 0; q < UNITS; ++q) s += rr[q];
    out[b0 + tid] = s;
  }
}

extern "C" void kernel_launch(void* const* d_in, const int* in_sizes, int n_in,
                              void* d_out, int out_size, void* d_ws, size_t ws_size,
                              hipStream_t stream) {
  const float* x       = (const float*)d_in[0];
  const float* gleak   = (const float*)d_in[1];
  const float* vleak   = (const float*)d_in[2];
  const float* cm      = (const float*)d_in[3];
  const float* sigma   = (const float*)d_in[4];
  const float* mu      = (const float*)d_in[5];
  const float* w_syn   = (const float*)d_in[6];
  const float* erev    = (const float*)d_in[7];
  const float* s_sigma = (const float*)d_in[8];
  const float* s_mu    = (const float*)d_in[9];
  const float* s_w     = (const float*)d_in[10];
  const float* s_erev  = (const float*)d_in[11];
  const float* input_w = (const float*)d_in[12];
  const float* input_b = (const float*)d_in[13];
  const float* out_w   = (const float*)d_in[14];
  const float* out_b   = (const float*)d_in[15];
  const float* fc_w    = (const float*)d_in[16];
  const float* fc_b    = (const float*)d_in[17];

  dim3 grid(512 / NB);
  dim3 block(1024);
  hipLaunchKernelGGL(ltc_fused, grid, block, 0, stream,
                     x, gleak, vleak, cm, sigma, mu, w_syn, erev,
                     s_sigma, s_mu, s_w, s_erev, input_w, input_b,
                     out_w, out_b, fc_w, fc_b, (float*)d_out);
}

// Round 3
// 3091.751 us; speedup vs baseline: 1.0650x; 1.0117x over previous
//
#include <hip/hip_runtime.h>

#define UNITS   128
#define TSTEPS  256
#define UNFOLDS 6
#define NB      2      // batch elements per block
#define NC      8      // i-chunks (threads per j)
#define CPT     16     // i's per thread
#define LOG2E   1.4426950408889634f
#define VPAD    160    // padded v row: 128 + 4 pad per 16
#define IDX(i)  ((i) + (((i) >> 4) << 2))

__device__ __forceinline__ float rcp_f(float x){
#if __has_builtin(__builtin_amdgcn_rcpf)
  return __builtin_amdgcn_rcpf(x);
#else
  return 1.0f / x;
#endif
}
__device__ __forceinline__ float exp2_f(float x){
#if __has_builtin(__builtin_amdgcn_exp2f)
  return __builtin_amdgcn_exp2f(x);
#else
  return __expf(x * 0.6931471805599453f);
#endif
}

// butterfly sum over the 8 consecutive lanes sharing one j:
// xor1, xor2 via quad_perm; xor7 (= other quad of the 8-group) via row_half_mirror
#define DPP_RED(x)                                                                                   \
  asm("v_add_f32_dpp %0, %1, %1 quad_perm:[1,0,3,2] row_mask:0xf bank_mask:0xf" : "=v"(x) : "v"(x)); \
  asm("v_add_f32_dpp %0, %1, %1 quad_perm:[2,3,0,1] row_mask:0xf bank_mask:0xf" : "=v"(x) : "v"(x)); \
  asm("v_add_f32_dpp %0, %1, %1 row_half_mirror row_mask:0xf bank_mask:0xf"     : "=v"(x) : "v"(x));

// one (i,j,b) synapse: y = (mu - v)*sigma*log2e ; sig = 1/(1+2^y)
#define ELEM(vv, kk, NUM, DEN)                                 \
  {                                                            \
    float y_  = fmaf((vv), ns2[kk], m2[kk]);                   \
    float e_  = exp2_f(y_);                                    \
    float sg_ = rcp_f(1.0f + e_);                              \
    NUM = fmaf(wn[kk], sg_, NUM);                              \
    DEN = fmaf(wd[kk], sg_, DEN);                              \
  }

__global__ __launch_bounds__(1024)
__attribute__((amdgpu_waves_per_eu(4, 4)))   // grid = 1 block/CU -> exactly 4 waves/EU;
                                             // give regalloc the full 128-VGPR budget so
                                             // the 64 param regs stay in arch VGPRs
void ltc_fused(
    const float* __restrict__ x,
    const float* __restrict__ gleak,
    const float* __restrict__ vleak,
    const float* __restrict__ cm,
    const float* __restrict__ sigma,
    const float* __restrict__ mu,
    const float* __restrict__ w_syn,
    const float* __restrict__ erev,
    const float* __restrict__ s_sigma,
    const float* __restrict__ s_mu,
    const float* __restrict__ s_w,
    const float* __restrict__ s_erev,
    const float* __restrict__ input_w,
    const float* __restrict__ input_b,
    const float* __restrict__ output_w,
    const float* __restrict__ output_b,
    const float* __restrict__ fc_w,
    const float* __restrict__ fc_b,
    float* __restrict__ out)
{
  __shared__ __align__(16) float vbuf[2][NB][VPAD];  // ping-pong state, bank-padded
  __shared__ float xs[NB][TSTEPS];
  __shared__ float red[NB][UNITS];

  const int tid = threadIdx.x;
  const int j   = tid >> 3;    // post-synaptic unit (0..127)
  const int c   = tid & 7;     // i-chunk (0..7)
  const int b0  = blockIdx.x * NB;

  // stage the whole input sequence for both batch elements (coalesced)
  if (tid < NB * TSTEPS) {
    int bb = tid >> 8;
    int tt = tid & (TSTEPS - 1);
    xs[bb][tt] = x[(b0 + bb) * TSTEPS + tt];
  }
  if (tid < NB * UNITS) {
    vbuf[0][tid >> 7][IDX(tid & (UNITS - 1))] = 0.0f;
  }

  // per-thread register-resident synapse params for (i in chunk, j)
  float ns2[CPT], m2[CPT], wn[CPT], wd[CPT];
#pragma unroll
  for (int k = 0; k < CPT; ++k) {
    int idx = (c * CPT + k) * UNITS + j;     // row = pre(i), col = post(j)
    float sg = sigma[idx] * LOG2E;
    ns2[k] = -sg;
    m2[k]  = mu[idx] * sg;
    float w = w_syn[idx];
    wn[k] = w * erev[idx];
    wd[k] = w;
  }

  // per-thread (per-j) scalars
  const float ss2n  = -s_sigma[j] * LOG2E;
  const float sm2   = s_mu[j] * (-ss2n);
  const float sw8   = s_w[j] * 0.125f;      // pre-divided by 8 for the lane-sum fold
  const float se_   = s_erev[j];
  const float gl    = gleak[j];
  const float glvl  = gl * vleak[j];
  const float cmt   = cm[j] * (float)UNFOLDS;
  const float dbase = cmt + gl + 1e-8f;
  const float iw    = input_w[0];
  const float ib    = input_b[0];

  __syncthreads();

  int cur = 0;
  const int cb = c * 20;  // padded chunk base (c*16 + c*4)
  for (int t = 0; t < TSTEPS; ++t) {
    // sensory conductances (fixed within unfolds), redundant per thread,
    // pre-scaled by 1/8 so the 8-lane butterfly sum restores them once
    float snum0, sden0, snum1, sden1;
    {
      float u = fmaf(xs[0][t], iw, ib);
      float e = exp2_f(fmaf(u, ss2n, sm2));
      float a = sw8 * rcp_f(1.0f + e);
      snum0 = a * se_; sden0 = a;
      u = fmaf(xs[1][t], iw, ib);
      e = exp2_f(fmaf(u, ss2n, sm2));
      a = sw8 * rcp_f(1.0f + e);
      snum1 = a * se_; sden1 = a;
    }
    for (int r = 0; r < UNFOLDS; ++r) {
      const float* __restrict__ v0 = vbuf[cur][0];
      const float* __restrict__ v1 = vbuf[cur][1];
      float vj0 = v0[IDX(j)];
      float vj1 = v1[IDX(j)];
      float num0 = snum0, den0 = sden0, num1 = snum1, den1 = sden1;
#pragma unroll
      for (int k = 0; k < CPT; k += 4) {
        float4 a4 = *(const float4*)&v0[cb + k];  // conflict-free broadcast
        float4 b4 = *(const float4*)&v1[cb + k];
        ELEM(a4.x, k + 0, num0, den0);
        ELEM(a4.y, k + 1, num0, den0);
        ELEM(a4.z, k + 2, num0, den0);
        ELEM(a4.w, k + 3, num0, den0);
        ELEM(b4.x, k + 0, num1, den1);
        ELEM(b4.y, k + 1, num1, den1);
        ELEM(b4.z, k + 2, num1, den1);
        ELEM(b4.w, k + 3, num1, den1);
      }
      // butterfly reduce over the 8 lanes sharing j — pure VALU, no LDS
      DPP_RED(num0); DPP_RED(den0); DPP_RED(num1); DPP_RED(den1);

      const int nxt = cur ^ 1;
      float nv0 = (fmaf(cmt, vj0, glvl) + num0) * rcp_f(dbase + den0);
      float nv1 = (fmaf(cmt, vj1, glvl) + num1) * rcp_f(dbase + den1);
      if (c == 0) {
        vbuf[nxt][0][IDX(j)] = nv0;
        vbuf[nxt][1][IDX(j)] = nv1;
      }
      __syncthreads();
      cur = nxt;
    }
  }

  // readout: out[b] = sum_j (v[j]*ow[j]+ob[j]) * fc_w[j] + fc_b
  if (c == 0) {
    float ow = output_w[j], ob = output_b[j], fw = fc_w[j];
    red[0][j] = fmaf(vbuf[cur][0][IDX(j)], ow, ob) * fw;
    red[1][j] = fmaf(vbuf[cur][1][IDX(j)], ow, ob) * fw;
  }
  __syncthreads();
  if (tid < NB) {
    float s = fc_b[0];
    const float* rr = red[tid];
    for (int q = 0; q < UNITS; ++q) s += rr[q];
    out[b0 + tid] = s;
  }
}

extern "C" void kernel_launch(void* const* d_in, const int* in_sizes, int n_in,
                              void* d_out, int out_size, void* d_ws, size_t ws_size,
                              hipStream_t stream) {
  const float* x       = (const float*)d_in[0];
  const float* gleak   = (const float*)d_in[1];
  const float* vleak   = (const float*)d_in[2];
  const float* cm      = (const float*)d_in[3];
  const float* sigma   = (const float*)d_in[4];
  const float* mu      = (const float*)d_in[5];
  const float* w_syn   = (const float*)d_in[6];
  const float* erev    = (const float*)d_in[7];
  const float* s_sigma = (const float*)d_in[8];
  const float* s_mu    = (const float*)d_in[9];
  const float* s_w     = (const float*)d_in[10];
  const float* s_erev  = (const float*)d_in[11];
  const float* input_w = (const float*)d_in[12];
  const float* input_b = (const float*)d_in[13];
  const float* out_w   = (const float*)d_in[14];
  const float* out_b   = (const float*)d_in[15];
  const float* fc_w    = (const float*)d_in[16];
  const float* fc_b    = (const float*)d_in[17];

  dim3 grid(512 / NB);
  dim3 block(1024);
  hipLaunchKernelGGL(ltc_fused, grid, block, 0, stream,
                     x, gleak, vleak, cm, sigma, mu, w_syn, erev,
                     s_sigma, s_mu, s_w, s_erev, input_w, input_b,
                     out_w, out_b, fc_w, fc_b, (float*)d_out);
}

// Round 5
// 2633.598 us; speedup vs baseline: 1.2503x; 1.1740x over previous
//
#include <hip/hip_runtime.h>

#define UNITS   128
#define TSTEPS  256
#define UNFOLDS 6
#define NB      2      // batch elements per block
#define NC      8      // i-chunks (threads per j)
#define CPT     16     // i's per thread
#define LOG2E   1.4426950408889634f
#define VPAD    160    // padded v row: 128 + 4 pad per 16
#define IDX(i)  ((i) + (((i) >> 4) << 2))

typedef float f32x2 __attribute__((ext_vector_type(2)));
typedef float f32x4 __attribute__((ext_vector_type(4)));

__device__ __forceinline__ float rcp_f(float x){
#if __has_builtin(__builtin_amdgcn_rcpf)
  return __builtin_amdgcn_rcpf(x);
#else
  return 1.0f / x;
#endif
}
__device__ __forceinline__ float exp2_f(float x){
#if __has_builtin(__builtin_amdgcn_exp2f)
  return __builtin_amdgcn_exp2f(x);
#else
  return __expf(x * 0.6931471805599453f);
#endif
}

// butterfly sum over the 8 consecutive lanes sharing one j:
// xor1, xor2 via quad_perm; xor7 (= other quad of the 8-group) via row_half_mirror
#define DPP_RED(x)                                                                                   \
  asm("v_add_f32_dpp %0, %1, %1 quad_perm:[1,0,3,2] row_mask:0xf bank_mask:0xf" : "=v"(x) : "v"(x)); \
  asm("v_add_f32_dpp %0, %1, %1 quad_perm:[2,3,0,1] row_mask:0xf bank_mask:0xf" : "=v"(x) : "v"(x)); \
  asm("v_add_f32_dpp %0, %1, %1 row_half_mirror row_mask:0xf bank_mask:0xf"     : "=v"(x) : "v"(x));

// two synapses (adjacent k, same batch) via packed f32 — compiler-selected
// v_pk_fma_f32 / v_pk_add_f32 from <2 x float> IR; element math identical to
// the scalar version (fma, +1, exp2, rcp, 2x fma).
#define ELEM2(vv2, kk, NUM2, DEN2)                                 \
  {                                                                \
    f32x2 y2 = __builtin_elementwise_fma(vv2, ns2p[kk], m2p[kk]);  \
    f32x2 e2;                                                      \
    e2.x = exp2_f(y2.x);                                           \
    e2.y = exp2_f(y2.y);                                           \
    e2 = e2 + one2;                                                \
    f32x2 s2;                                                      \
    s2.x = rcp_f(e2.x);                                            \
    s2.y = rcp_f(e2.y);                                            \
    NUM2 = __builtin_elementwise_fma(s2, wnp[kk], NUM2);           \
    DEN2 = __builtin_elementwise_fma(s2, wdp[kk], DEN2);           \
  }

__global__ __launch_bounds__(1024)
__attribute__((amdgpu_waves_per_eu(4, 4)))
void ltc_fused(
    const float* __restrict__ x,
    const float* __restrict__ gleak,
    const float* __restrict__ vleak,
    const float* __restrict__ cm,
    const float* __restrict__ sigma,
    const float* __restrict__ mu,
    const float* __restrict__ w_syn,
    const float* __restrict__ erev,
    const float* __restrict__ s_sigma,
    const float* __restrict__ s_mu,
    const float* __restrict__ s_w,
    const float* __restrict__ s_erev,
    const float* __restrict__ input_w,
    const float* __restrict__ input_b,
    const float* __restrict__ output_w,
    const float* __restrict__ output_b,
    const float* __restrict__ fc_w,
    const float* __restrict__ fc_b,
    float* __restrict__ out)
{
  __shared__ __align__(16) float vbuf[2][NB][VPAD];  // ping-pong state, bank-padded
  __shared__ float xs[NB][TSTEPS];
  __shared__ float red[NB][UNITS];

  const int tid = threadIdx.x;
  const int j   = tid >> 3;    // post-synaptic unit (0..127)
  const int c   = tid & 7;     // i-chunk (0..7)
  const int b0  = blockIdx.x * NB;

  // stage the whole input sequence for both batch elements (coalesced)
  if (tid < NB * TSTEPS) {
    int bb = tid >> 8;
    int tt = tid & (TSTEPS - 1);
    xs[bb][tt] = x[(b0 + bb) * TSTEPS + tt];
  }
  if (tid < NB * UNITS) {
    vbuf[0][tid >> 7][IDX(tid & (UNITS - 1))] = 0.0f;
  }

  // per-thread register-resident synapse params, packed as pairs over k
  f32x2 ns2p[CPT/2], m2p[CPT/2], wnp[CPT/2], wdp[CPT/2];
#pragma unroll
  for (int k2 = 0; k2 < CPT/2; ++k2) {
    int iA = (c * CPT + 2*k2) * UNITS + j;   // row = pre(i), col = post(j)
    int iB = iA + UNITS;
    float sgA = sigma[iA] * LOG2E, sgB = sigma[iB] * LOG2E;
    ns2p[k2] = (f32x2){-sgA, -sgB};
    m2p[k2]  = (f32x2){mu[iA] * sgA, mu[iB] * sgB};
    float wA = w_syn[iA], wB = w_syn[iB];
    wnp[k2] = (f32x2){wA * erev[iA], wB * erev[iB]};
    wdp[k2] = (f32x2){wA, wB};
  }
  const f32x2 one2 = {1.0f, 1.0f};

  // per-thread (per-j) scalars
  const float ss2n  = -s_sigma[j] * LOG2E;
  const float sm2   = s_mu[j] * (-ss2n);
  const float sw8   = s_w[j] * 0.125f;      // pre-divided by 8 for the lane-sum fold
  const float se_   = s_erev[j];
  const float gl    = gleak[j];
  const float glvl  = gl * vleak[j];
  const float cmt   = cm[j] * (float)UNFOLDS;
  const float dbase = cmt + gl + 1e-8f;
  const float iw    = input_w[0];
  const float ib    = input_b[0];

  __syncthreads();

  int cur = 0;
  const int cb = c * 20;  // padded chunk base (c*16 + c*4)
  for (int t = 0; t < TSTEPS; ++t) {
    // sensory conductances (fixed within unfolds), redundant per thread,
    // pre-scaled by 1/8 so the 8-lane butterfly sum restores them once
    float snum0, sden0, snum1, sden1;
    {
      float u = fmaf(xs[0][t], iw, ib);
      float e = exp2_f(fmaf(u, ss2n, sm2));
      float a = sw8 * rcp_f(1.0f + e);
      snum0 = a * se_; sden0 = a;
      u = fmaf(xs[1][t], iw, ib);
      e = exp2_f(fmaf(u, ss2n, sm2));
      a = sw8 * rcp_f(1.0f + e);
      snum1 = a * se_; sden1 = a;
    }
    for (int r = 0; r < UNFOLDS; ++r) {
      const float* __restrict__ v0 = vbuf[cur][0];
      const float* __restrict__ v1 = vbuf[cur][1];
      float vj0 = v0[IDX(j)];
      float vj1 = v1[IDX(j)];
      f32x2 n0 = {snum0, 0.f}, d0 = {sden0, 0.f};
      f32x2 n1 = {snum1, 0.f}, d1 = {sden1, 0.f};
#pragma unroll
      for (int k = 0; k < CPT; k += 4) {
        f32x4 a4 = *(const f32x4*)&v0[cb + k];  // conflict-free broadcast
        f32x4 b4 = *(const f32x4*)&v1[cb + k];
        f32x2 alo = a4.xy, ahi = a4.zw;
        f32x2 blo = b4.xy, bhi = b4.zw;
        ELEM2(alo, (k/2),     n0, d0);
        ELEM2(ahi, (k/2 + 1), n0, d0);
        ELEM2(blo, (k/2),     n1, d1);
        ELEM2(bhi, (k/2 + 1), n1, d1);
      }
      // horizontal over the packed pair, then butterfly over the 8 lanes
      float num0 = n0.x + n0.y, den0 = d0.x + d0.y;
      float num1 = n1.x + n1.y, den1 = d1.x + d1.y;
      DPP_RED(num0); DPP_RED(den0); DPP_RED(num1); DPP_RED(den1);

      const int nxt = cur ^ 1;
      float nv0 = (fmaf(cmt, vj0, glvl) + num0) * rcp_f(dbase + den0);
      float nv1 = (fmaf(cmt, vj1, glvl) + num1) * rcp_f(dbase + den1);
      if (c == 0) {
        vbuf[nxt][0][IDX(j)] = nv0;
        vbuf[nxt][1][IDX(j)] = nv1;
      }
      __syncthreads();
      cur = nxt;
    }
  }

  // readout: out[b] = sum_j (v[j]*ow[j]+ob[j]) * fc_w[j] + fc_b
  if (c == 0) {
    float ow = output_w[j], ob = output_b[j], fw = fc_w[j];
    red[0][j] = fmaf(vbuf[cur][0][IDX(j)], ow, ob) * fw;
    red[1][j] = fmaf(vbuf[cur][1][IDX(j)], ow, ob) * fw;
  }
  __syncthreads();
  if (tid < NB) {
    float s = fc_b[0];
    const float* rr = red[tid];
    for (int q = 0; q < UNITS; ++q) s += rr[q];
    out[b0 + tid] = s;
  }
}

extern "C" void kernel_launch(void* const* d_in, const int* in_sizes, int n_in,
                              void* d_out, int out_size, void* d_ws, size_t ws_size,
                              hipStream_t stream) {
  const float* x       = (const float*)d_in[0];
  const float* gleak   = (const float*)d_in[1];
  const float* vleak   = (const float*)d_in[2];
  const float* cm      = (const float*)d_in[3];
  const float* sigma   = (const float*)d_in[4];
  const float* mu      = (const float*)d_in[5];
  const float* w_syn   = (const float*)d_in[6];
  const float* erev    = (const float*)d_in[7];
  const float* s_sigma = (const float*)d_in[8];
  const float* s_mu    = (const float*)d_in[9];
  const float* s_w     = (const float*)d_in[10];
  const float* s_erev  = (const float*)d_in[11];
  const float* input_w = (const float*)d_in[12];
  const float* input_b = (const float*)d_in[13];
  const float* out_w   = (const float*)d_in[14];
  const float* out_b   = (const float*)d_in[15];
  const float* fc_w    = (const float*)d_in[16];
  const float* fc_b    = (const float*)d_in[17];

  dim3 grid(512 / NB);
  dim3 block(1024);
  hipLaunchKernelGGL(ltc_fused, grid, block, 0, stream,
                     x, gleak, vleak, cm, sigma, mu, w_syn, erev,
                     s_sigma, s_mu, s_w, s_erev, input_w, input_b,
                     out_w, out_b, fc_w, fc_b, (float*)d_out);
}

// Round 6
// 2558.420 us; speedup vs baseline: 1.2870x; 1.0294x over previous
//
#include <hip/hip_runtime.h>

#define UNITS   128
#define TSTEPS  256
#define UNFOLDS 6
#define NB      2      // batch elements per block
#define NC      8      // i-chunks (threads per j)
#define CPT     16     // i's per thread
#define LOG2E   1.4426950408889634f
#define VPAD    160    // padded v row: 128 + 4 pad per 16
#define IDX(i)  ((i) + (((i) >> 4) << 2))

typedef float f32x2 __attribute__((ext_vector_type(2)));
typedef float f32x4 __attribute__((ext_vector_type(4)));

__device__ __forceinline__ float rcp_f(float x){
#if __has_builtin(__builtin_amdgcn_rcpf)
  return __builtin_amdgcn_rcpf(x);
#else
  return 1.0f / x;
#endif
}
__device__ __forceinline__ float exp2_f(float x){
#if __has_builtin(__builtin_amdgcn_exp2f)
  return __builtin_amdgcn_exp2f(x);
#else
  return __expf(x * 0.6931471805599453f);
#endif
}

// butterfly sum over the 8 consecutive lanes sharing one j:
// xor1, xor2 via quad_perm; xor7 (= other quad of the 8-group) via row_half_mirror
#define DPP_RED(x)                                                                                   \
  asm("v_add_f32_dpp %0, %1, %1 quad_perm:[1,0,3,2] row_mask:0xf bank_mask:0xf" : "=v"(x) : "v"(x)); \
  asm("v_add_f32_dpp %0, %1, %1 quad_perm:[2,3,0,1] row_mask:0xf bank_mask:0xf" : "=v"(x) : "v"(x)); \
  asm("v_add_f32_dpp %0, %1, %1 row_half_mirror row_mask:0xf bank_mask:0xf"     : "=v"(x) : "v"(x));

// four synapses (same batch, adjacent k) with ONE v_rcp via batch inversion:
//   p=(1+e0,1+e1), q=(1+e2,1+e3); m=p*q=(ac,bd); r=rcp(ac*bd);
//   rr=(r*bd, r*ac)=(1/ac,1/bd); 1/p = rr*q; 1/q = rr*p.  Exact to a few ulp.
//   No overflow: |v|<=1 (|num|<=den induction) => y<=20.8 => a<=1.8e6 => abcd<=1.1e25.
#define ELEM4(vlo, vhi, kk, NUM2, DEN2)                                 \
  {                                                                     \
    f32x2 ylo = __builtin_elementwise_fma(vlo, ns2p[kk],   m2p[kk]);    \
    f32x2 yhi = __builtin_elementwise_fma(vhi, ns2p[kk+1], m2p[kk+1]);  \
    f32x2 p2, q2;                                                       \
    p2.x = exp2_f(ylo.x);  p2.y = exp2_f(ylo.y);                        \
    q2.x = exp2_f(yhi.x);  q2.y = exp2_f(yhi.y);                        \
    p2 = p2 + one2;                                                     \
    q2 = q2 + one2;                                                     \
    f32x2 m2_ = p2 * q2;                                                \
    float P_  = m2_.x * m2_.y;                                          \
    float r_  = rcp_f(P_);                                              \
    f32x2 rr; rr.x = r_ * m2_.y; rr.y = r_ * m2_.x;                     \
    f32x2 slo = rr * q2;                                                \
    f32x2 shi = rr * p2;                                                \
    NUM2 = __builtin_elementwise_fma(slo, wnp[kk],   NUM2);             \
    DEN2 = __builtin_elementwise_fma(slo, wdp[kk],   DEN2);             \
    NUM2 = __builtin_elementwise_fma(shi, wnp[kk+1], NUM2);             \
    DEN2 = __builtin_elementwise_fma(shi, wdp[kk+1], DEN2);             \
  }

__global__ __launch_bounds__(1024)
__attribute__((amdgpu_waves_per_eu(4, 4)))
void ltc_fused(
    const float* __restrict__ x,
    const float* __restrict__ gleak,
    const float* __restrict__ vleak,
    const float* __restrict__ cm,
    const float* __restrict__ sigma,
    const float* __restrict__ mu,
    const float* __restrict__ w_syn,
    const float* __restrict__ erev,
    const float* __restrict__ s_sigma,
    const float* __restrict__ s_mu,
    const float* __restrict__ s_w,
    const float* __restrict__ s_erev,
    const float* __restrict__ input_w,
    const float* __restrict__ input_b,
    const float* __restrict__ output_w,
    const float* __restrict__ output_b,
    const float* __restrict__ fc_w,
    const float* __restrict__ fc_b,
    float* __restrict__ out)
{
  __shared__ __align__(16) float vbuf[2][NB][VPAD];  // ping-pong state, bank-padded
  __shared__ float xs[NB][TSTEPS];
  __shared__ float red[NB][UNITS];

  const int tid = threadIdx.x;
  const int j   = tid >> 3;    // post-synaptic unit (0..127)
  const int c   = tid & 7;     // i-chunk (0..7)
  const int b0  = blockIdx.x * NB;

  // stage the whole input sequence for both batch elements (coalesced)
  if (tid < NB * TSTEPS) {
    int bb = tid >> 8;
    int tt = tid & (TSTEPS - 1);
    xs[bb][tt] = x[(b0 + bb) * TSTEPS + tt];
  }
  if (tid < NB * UNITS) {
    vbuf[0][tid >> 7][IDX(tid & (UNITS - 1))] = 0.0f;
  }

  // per-thread register-resident synapse params, packed as pairs over k
  f32x2 ns2p[CPT/2], m2p[CPT/2], wnp[CPT/2], wdp[CPT/2];
#pragma unroll
  for (int k2 = 0; k2 < CPT/2; ++k2) {
    int iA = (c * CPT + 2*k2) * UNITS + j;   // row = pre(i), col = post(j)
    int iB = iA + UNITS;
    float sgA = sigma[iA] * LOG2E, sgB = sigma[iB] * LOG2E;
    ns2p[k2] = (f32x2){-sgA, -sgB};
    m2p[k2]  = (f32x2){mu[iA] * sgA, mu[iB] * sgB};
    float wA = w_syn[iA], wB = w_syn[iB];
    wnp[k2] = (f32x2){wA * erev[iA], wB * erev[iB]};
    wdp[k2] = (f32x2){wA, wB};
  }
  const f32x2 one2 = {1.0f, 1.0f};

  // per-thread (per-j) scalars
  const float ss2n  = -s_sigma[j] * LOG2E;
  const float sm2   = s_mu[j] * (-ss2n);
  const float sw8   = s_w[j] * 0.125f;      // pre-divided by 8 for the lane-sum fold
  const float se_   = s_erev[j];
  const float gl    = gleak[j];
  const float glvl  = gl * vleak[j];
  const float cmt   = cm[j] * (float)UNFOLDS;
  const float dbase = cmt + gl + 1e-8f;
  const float iw    = input_w[0];
  const float ib    = input_b[0];

  __syncthreads();

  int cur = 0;
  const int cb = c * 20;  // padded chunk base (c*16 + c*4)
  for (int t = 0; t < TSTEPS; ++t) {
    // sensory conductances (fixed within unfolds), redundant per thread,
    // pre-scaled by 1/8 so the 8-lane butterfly sum restores them once
    float snum0, sden0, snum1, sden1;
    {
      float u = fmaf(xs[0][t], iw, ib);
      float e = exp2_f(fmaf(u, ss2n, sm2));
      float a = sw8 * rcp_f(1.0f + e);
      snum0 = a * se_; sden0 = a;
      u = fmaf(xs[1][t], iw, ib);
      e = exp2_f(fmaf(u, ss2n, sm2));
      a = sw8 * rcp_f(1.0f + e);
      snum1 = a * se_; sden1 = a;
    }
    for (int r = 0; r < UNFOLDS; ++r) {
      const float* __restrict__ v0 = vbuf[cur][0];
      const float* __restrict__ v1 = vbuf[cur][1];
      float vj0 = v0[IDX(j)];
      float vj1 = v1[IDX(j)];
      f32x2 n0 = {snum0, 0.f}, d0 = {sden0, 0.f};
      f32x2 n1 = {snum1, 0.f}, d1 = {sden1, 0.f};
#pragma unroll
      for (int k = 0; k < CPT; k += 4) {
        f32x4 a4 = *(const f32x4*)&v0[cb + k];  // conflict-free broadcast
        f32x4 b4 = *(const f32x4*)&v1[cb + k];
        f32x2 alo = a4.xy, ahi = a4.zw;
        f32x2 blo = b4.xy, bhi = b4.zw;
        ELEM4(alo, ahi, (k/2), n0, d0);
        ELEM4(blo, bhi, (k/2), n1, d1);
      }
      // horizontal over the packed pair, then butterfly over the 8 lanes
      float num0 = n0.x + n0.y, den0 = d0.x + d0.y;
      float num1 = n1.x + n1.y, den1 = d1.x + d1.y;
      DPP_RED(num0); DPP_RED(den0); DPP_RED(num1); DPP_RED(den1);

      const int nxt = cur ^ 1;
      float nv0 = (fmaf(cmt, vj0, glvl) + num0) * rcp_f(dbase + den0);
      float nv1 = (fmaf(cmt, vj1, glvl) + num1) * rcp_f(dbase + den1);
      if (c == 0) {
        vbuf[nxt][0][IDX(j)] = nv0;
        vbuf[nxt][1][IDX(j)] = nv1;
      }
      __syncthreads();
      cur = nxt;
    }
  }

  // readout: out[b] = sum_j (v[j]*ow[j]+ob[j]) * fc_w[j] + fc_b
  if (c == 0) {
    float ow = output_w[j], ob = output_b[j], fw = fc_w[j];
    red[0][j] = fmaf(vbuf[cur][0][IDX(j)], ow, ob) * fw;
    red[1][j] = fmaf(vbuf[cur][1][IDX(j)], ow, ob) * fw;
  }
  __syncthreads();
  if (tid < NB) {
    float s = fc_b[0];
    const float* rr = red[tid];
    for (int q = 0; q < UNITS; ++q) s += rr[q];
    out[b0 + tid] = s;
  }
}

extern "C" void kernel_launch(void* const* d_in, const int* in_sizes, int n_in,
                              void* d_out, int out_size, void* d_ws, size_t ws_size,
                              hipStream_t stream) {
  const float* x       = (const float*)d_in[0];
  const float* gleak   = (const float*)d_in[1];
  const float* vleak   = (const float*)d_in[2];
  const float* cm      = (const float*)d_in[3];
  const float* sigma   = (const float*)d_in[4];
  const float* mu      = (const float*)d_in[5];
  const float* w_syn   = (const float*)d_in[6];
  const float* erev    = (const float*)d_in[7];
  const float* s_sigma = (const float*)d_in[8];
  const float* s_mu    = (const float*)d_in[9];
  const float* s_w     = (const float*)d_in[10];
  const float* s_erev  = (const float*)d_in[11];
  const float* input_w = (const float*)d_in[12];
  const float* input_b = (const float*)d_in[13];
  const float* out_w   = (const float*)d_in[14];
  const float* out_b   = (const float*)d_in[15];
  const float* fc_w    = (const float*)d_in[16];
  const float* fc_b    = (const float*)d_in[17];

  dim3 grid(512 / NB);
  dim3 block(1024);
  hipLaunchKernelGGL(ltc_fused, grid, block, 0, stream,
                     x, gleak, vleak, cm, sigma, mu, w_syn, erev,
                     s_sigma, s_mu, s_w, s_erev, input_w, input_b,
                     out_w, out_b, fc_w, fc_b, (float*)d_out);
}

// Round 7
// 2554.042 us; speedup vs baseline: 1.2893x; 1.0017x over previous
//
#include <hip/hip_runtime.h>

#define UNITS   128
#define TSTEPS  256
#define UNFOLDS 6
#define NB      2      // batch elements per block
#define NC      8      // i-chunks (threads per j)
#define CPT     16     // i's per thread
#define LOG2E   1.4426950408889634f
#define VPAD    160    // padded v row: 128 + 4 pad per 16
#define IDX(i)  ((i) + (((i) >> 4) << 2))

typedef float f32x2 __attribute__((ext_vector_type(2)));
typedef float f32x4 __attribute__((ext_vector_type(4)));

__device__ __forceinline__ float rcp_f(float x){
#if __has_builtin(__builtin_amdgcn_rcpf)
  return __builtin_amdgcn_rcpf(x);
#else
  return 1.0f / x;
#endif
}
__device__ __forceinline__ float exp2_f(float x){
#if __has_builtin(__builtin_amdgcn_exp2f)
  return __builtin_amdgcn_exp2f(x);
#else
  return __expf(x * 0.6931471805599453f);
#endif
}

// butterfly sum over the 8 consecutive lanes sharing one j:
// xor1, xor2 via quad_perm; xor7 (= other quad of the 8-group) via row_half_mirror
#define DPP_RED(x)                                                                                   \
  asm("v_add_f32_dpp %0, %1, %1 quad_perm:[1,0,3,2] row_mask:0xf bank_mask:0xf" : "=v"(x) : "v"(x)); \
  asm("v_add_f32_dpp %0, %1, %1 quad_perm:[2,3,0,1] row_mask:0xf bank_mask:0xf" : "=v"(x) : "v"(x)); \
  asm("v_add_f32_dpp %0, %1, %1 row_half_mirror row_mask:0xf bank_mask:0xf"     : "=v"(x) : "v"(x));

// four synapses = same k-pair for BOTH batches, one v_rcp via batch inversion.
// The two exp2 sub-chains (batch A, batch B) are independent and join only at
// m = pA*pB — half the critical path of the all-same-batch grouping (R6).
//   pA=(1+eA0,1+eA1), pB=(1+eB0,1+eB1); m=pA*pB; r=rcp(m.x*m.y);
//   rr=(r*m.y, r*m.x); 1/pA = rr*pB; 1/pB = rr*pA.   Exact to a few ulp.
//   No overflow: |v|<=1 => y<=20.8 => factor<=1.8e6 => product<=1.1e25.
#define ELEM4X(vA, vB, kk)                                              \
  {                                                                     \
    f32x2 yA = __builtin_elementwise_fma(vA, ns2p[kk], m2p[kk]);        \
    f32x2 yB = __builtin_elementwise_fma(vB, ns2p[kk], m2p[kk]);        \
    f32x2 pA, pB;                                                       \
    pA.x = exp2_f(yA.x);  pA.y = exp2_f(yA.y);                          \
    pB.x = exp2_f(yB.x);  pB.y = exp2_f(yB.y);                          \
    pA = pA + one2;                                                     \
    pB = pB + one2;                                                     \
    f32x2 m2_ = pA * pB;                                                \
    float P_  = m2_.x * m2_.y;                                          \
    float r_  = rcp_f(P_);                                              \
    f32x2 rr; rr.x = r_ * m2_.y; rr.y = r_ * m2_.x;                     \
    f32x2 sA = rr * pB;                                                 \
    f32x2 sB = rr * pA;                                                 \
    n0 = __builtin_elementwise_fma(sA, wnp[kk], n0);                    \
    d0 = __builtin_elementwise_fma(sA, wdp[kk], d0);                    \
    n1 = __builtin_elementwise_fma(sB, wnp[kk], n1);                    \
    d1 = __builtin_elementwise_fma(sB, wdp[kk], d1);                    \
  }

__global__ __launch_bounds__(1024)
__attribute__((amdgpu_waves_per_eu(4, 4)))
void ltc_fused(
    const float* __restrict__ x,
    const float* __restrict__ gleak,
    const float* __restrict__ vleak,
    const float* __restrict__ cm,
    const float* __restrict__ sigma,
    const float* __restrict__ mu,
    const float* __restrict__ w_syn,
    const float* __restrict__ erev,
    const float* __restrict__ s_sigma,
    const float* __restrict__ s_mu,
    const float* __restrict__ s_w,
    const float* __restrict__ s_erev,
    const float* __restrict__ input_w,
    const float* __restrict__ input_b,
    const float* __restrict__ output_w,
    const float* __restrict__ output_b,
    const float* __restrict__ fc_w,
    const float* __restrict__ fc_b,
    float* __restrict__ out)
{
  __shared__ __align__(16) float vbuf[2][NB][VPAD];  // ping-pong state, bank-padded
  __shared__ float xs[NB][TSTEPS];
  __shared__ float red[NB][UNITS];

  const int tid = threadIdx.x;
  const int j   = tid >> 3;    // post-synaptic unit (0..127)
  const int c   = tid & 7;     // i-chunk (0..7)
  const int b0  = blockIdx.x * NB;

  // stage the whole input sequence for both batch elements (coalesced)
  if (tid < NB * TSTEPS) {
    int bb = tid >> 8;
    int tt = tid & (TSTEPS - 1);
    xs[bb][tt] = x[(b0 + bb) * TSTEPS + tt];
  }
  if (tid < NB * UNITS) {
    vbuf[0][tid >> 7][IDX(tid & (UNITS - 1))] = 0.0f;
  }

  // per-thread register-resident synapse params, packed as pairs over k
  f32x2 ns2p[CPT/2], m2p[CPT/2], wnp[CPT/2], wdp[CPT/2];
#pragma unroll
  for (int k2 = 0; k2 < CPT/2; ++k2) {
    int iA = (c * CPT + 2*k2) * UNITS + j;   // row = pre(i), col = post(j)
    int iB = iA + UNITS;
    float sgA = sigma[iA] * LOG2E, sgB = sigma[iB] * LOG2E;
    ns2p[k2] = (f32x2){-sgA, -sgB};
    m2p[k2]  = (f32x2){mu[iA] * sgA, mu[iB] * sgB};
    float wA = w_syn[iA], wB = w_syn[iB];
    wnp[k2] = (f32x2){wA * erev[iA], wB * erev[iB]};
    wdp[k2] = (f32x2){wA, wB};
  }
  const f32x2 one2 = {1.0f, 1.0f};

  // per-thread (per-j) scalars
  const float ss2n  = -s_sigma[j] * LOG2E;
  const float sm2   = s_mu[j] * (-ss2n);
  const float sw8   = s_w[j] * 0.125f;      // pre-divided by 8 for the lane-sum fold
  const float se_   = s_erev[j];
  const float gl    = gleak[j];
  const float glvl  = gl * vleak[j];
  const float cmt   = cm[j] * (float)UNFOLDS;
  const float dbase = cmt + gl + 1e-8f;
  const float iw    = input_w[0];
  const float ib    = input_b[0];

  __syncthreads();

  int cur = 0;
  const int cb = c * 20;  // padded chunk base (c*16 + c*4)
  for (int t = 0; t < TSTEPS; ++t) {
    // sensory conductances (fixed within unfolds), redundant per thread,
    // pre-scaled by 1/8 so the 8-lane butterfly sum restores them once
    float snum0, sden0, snum1, sden1;
    {
      float u = fmaf(xs[0][t], iw, ib);
      float e = exp2_f(fmaf(u, ss2n, sm2));
      float a = sw8 * rcp_f(1.0f + e);
      snum0 = a * se_; sden0 = a;
      u = fmaf(xs[1][t], iw, ib);
      e = exp2_f(fmaf(u, ss2n, sm2));
      a = sw8 * rcp_f(1.0f + e);
      snum1 = a * se_; sden1 = a;
    }
    for (int r = 0; r < UNFOLDS; ++r) {
      const float* __restrict__ v0 = vbuf[cur][0];
      const float* __restrict__ v1 = vbuf[cur][1];
      float vj0 = v0[IDX(j)];
      float vj1 = v1[IDX(j)];
      f32x2 n0 = {snum0, 0.f}, d0 = {sden0, 0.f};
      f32x2 n1 = {snum1, 0.f}, d1 = {sden1, 0.f};
#pragma unroll
      for (int k = 0; k < CPT; k += 4) {
        f32x4 a4 = *(const f32x4*)&v0[cb + k];  // conflict-free broadcast
        f32x4 b4 = *(const f32x4*)&v1[cb + k];
        f32x2 alo = a4.xy, ahi = a4.zw;
        f32x2 blo = b4.xy, bhi = b4.zw;
        ELEM4X(alo, blo, (k/2));        // cross-batch group: short chains
        ELEM4X(ahi, bhi, (k/2 + 1));
      }
      // horizontal over the packed pair, then butterfly over the 8 lanes
      float num0 = n0.x + n0.y, den0 = d0.x + d0.y;
      float num1 = n1.x + n1.y, den1 = d1.x + d1.y;
      DPP_RED(num0); DPP_RED(den0); DPP_RED(num1); DPP_RED(den1);

      const int nxt = cur ^ 1;
      // batched epilogue reciprocal (independent chains join once)
      float D0 = dbase + den0, D1 = dbase + den1;
      float rD = rcp_f(D0 * D1);
      float nv0 = (fmaf(cmt, vj0, glvl) + num0) * (rD * D1);
      float nv1 = (fmaf(cmt, vj1, glvl) + num1) * (rD * D0);
      if (c == 0) {
        vbuf[nxt][0][IDX(j)] = nv0;
        vbuf[nxt][1][IDX(j)] = nv1;
      }
      __syncthreads();
      cur = nxt;
    }
  }

  // readout: out[b] = sum_j (v[j]*ow[j]+ob[j]) * fc_w[j] + fc_b
  if (c == 0) {
    float ow = output_w[j], ob = output_b[j], fw = fc_w[j];
    red[0][j] = fmaf(vbuf[cur][0][IDX(j)], ow, ob) * fw;
    red[1][j] = fmaf(vbuf[cur][1][IDX(j)], ow, ob) * fw;
  }
  __syncthreads();
  if (tid < NB) {
    float s = fc_b[0];
    const float* rr = red[tid];
    for (int q = 0; q < UNITS; ++q) s += rr[q];
    out[b0 + tid] = s;
  }
}

extern "C" void kernel_launch(void* const* d_in, const int* in_sizes, int n_in,
                              void* d_out, int out_size, void* d_ws, size_t ws_size,
                              hipStream_t stream) {
  const float* x       = (const float*)d_in[0];
  const float* gleak   = (const float*)d_in[1];
  const float* vleak   = (const float*)d_in[2];
  const float* cm      = (const float*)d_in[3];
  const float* sigma   = (const float*)d_in[4];
  const float* mu      = (const float*)d_in[5];
  const float* w_syn   = (const float*)d_in[6];
  const float* erev    = (const float*)d_in[7];
  const float* s_sigma = (const float*)d_in[8];
  const float* s_mu    = (const float*)d_in[9];
  const float* s_w     = (const float*)d_in[10];
  const float* s_erev  = (const float*)d_in[11];
  const float* input_w = (const float*)d_in[12];
  const float* input_b = (const float*)d_in[13];
  const float* out_w   = (const float*)d_in[14];
  const float* out_b   = (const float*)d_in[15];
  const float* fc_w    = (const float*)d_in[16];
  const float* fc_b    = (const float*)d_in[17];

  dim3 grid(512 / NB);
  dim3 block(1024);
  hipLaunchKernelGGL(ltc_fused, grid, block, 0, stream,
                     x, gleak, vleak, cm, sigma, mu, w_syn, erev,
                     s_sigma, s_mu, s_w, s_erev, input_w, input_b,
                     out_w, out_b, fc_w, fc_b, (float*)d_out);
}